// Round 11
// baseline (136.370 us; speedup 1.0000x reference)
//
#include <hip/hip_runtime.h>
#include <hip/hip_bf16.h>

// Self-guided-filter loss, fused per 32x32 tile. v11 = v9 with stage-1 split
// into two vertical halves -> LDS 26,880 B -> 6 blocks/CU (24 waves, +50% TLP).
//  - P2a/P2b: global -> h1 (31 rows) horizontal 11-sums; 186 tasks each.
//  - P4a/P4b: vertical 11-sums h1 -> A,B (21 rows each); 77 tasks, reg-saved.
//  - P6: horizontal 11-sums A,B -> h2 (aliases h1 region); 168 tasks.
//  - P7: direct 11-tap vertical over h2 + finalize; 256 tasks; flit in regs.
//  - XCD-chunked bijective block swizzle.
// (8,3,512,512) fp32, RADIUS=5 (k=11), EPS=1e-6.

#define W 512
#define TB 32
#define H1STR 44   // h1: 31 rows, cols 0..41 valid (42,43 never written, never consumed)
#define ABSTR 44   // A,B: 42 rows, cols 0..41 valid (42,43 written junk, never consumed)
#define H2STR 36   // h2: 42 rows, cols 0..31

// Region1: h1 (stage 1) / h2 (stage 2); lifetimes disjoint.
#define O_H1X 0        // 31*44 = 1364
#define O_H1Y 1364
#define O_H2A 0        // 42*36 = 1512
#define O_H2B 1512
// Region2: A,B
#define O_A   3024     // 42*44 = 1848
#define O_B   4872
#define S_FLOATS 6720  // 26,880 B -> 6 blocks/CU

#define NBLK_X 16
#define NBLK_Y 16
#define NPLANES 24
#define NWG (NBLK_X*NBLK_Y*NPLANES)     // 6144, % 8 == 0
#define NPARTIALS NWG
#define TOTAL_ELEMS 6291456.0
#define INV121 (1.0f/121.0f)

__device__ __forceinline__ float4 ld4(const float* p) { return *(const float4*)p; }

// ---- P2 half: global -> h1 horizontal 11-sums of x, x^2. 186 tasks.
// h1 buf row r <-> img row (IMGROW0)+r, r=0..30. h1 col j = sum img cols
// tx0-10+j .. tx0+j of x (o) and x^2 (u).
#define P2_HALF(IMGROW0)                                                      \
    if (tid < 186) {                                                          \
        int r = tid / 6, cg = tid - r * 6;                                    \
        int j0 = cg * 8;                                                      \
        float* hx = &S[O_H1X + r * H1STR + j0];                               \
        float* hy = &S[O_H1Y + r * H1STR + j0];                               \
        int gy = (IMGROW0) + r;                                               \
        float w[20];                                                          \
        if ((unsigned)gy < (unsigned)W) {                                     \
            const float* Xr = X + (size_t)gy * W;                             \
            int gx0 = tx0 - 12 + j0;                                          \
            if (gx0 >= 0 && gx0 + 20 <= W) {                                  \
                const float4* p = (const float4*)(Xr + gx0);                  \
                float4 v0 = p[0], v1 = p[1], v2 = p[2], v3 = p[3], v4 = p[4]; \
                w[0]=v0.x;  w[1]=v0.y;  w[2]=v0.z;  w[3]=v0.w;                \
                w[4]=v1.x;  w[5]=v1.y;  w[6]=v1.z;  w[7]=v1.w;                \
                w[8]=v2.x;  w[9]=v2.y;  w[10]=v2.z; w[11]=v2.w;               \
                w[12]=v3.x; w[13]=v3.y; w[14]=v3.z; w[15]=v3.w;               \
                w[16]=v4.x; w[17]=v4.y; w[18]=v4.z; w[19]=v4.w;               \
            } else {                                                          \
                _Pragma("unroll")                                             \
                for (int k = 0; k < 20; ++k) {                                \
                    int gx = gx0 + k;                                         \
                    w[k] = ((unsigned)gx < (unsigned)W) ? Xr[gx] : 0.f;       \
                }                                                             \
            }                                                                 \
        } else {                                                              \
            _Pragma("unroll")                                                 \
            for (int k = 0; k < 20; ++k) w[k] = 0.f;                          \
        }                                                                     \
        float o[8], u[8];                                                     \
        float s = w[2]+w[3]+w[4]+w[5]+w[6]+w[7]+w[8]+w[9]+w[10]+w[11]+w[12];  \
        o[0] = s;                                                             \
        _Pragma("unroll")                                                     \
        for (int k = 1; k < 8; ++k) { s += w[12+k] - w[1+k]; o[k] = s; }      \
        float sq[20];                                                         \
        _Pragma("unroll")                                                     \
        for (int k = 2; k < 20; ++k) sq[k] = w[k] * w[k];                     \
        float s2 = sq[2]+sq[3]+sq[4]+sq[5]+sq[6]+sq[7]+sq[8]+sq[9]+sq[10]     \
                 +sq[11]+sq[12];                                              \
        u[0] = s2;                                                            \
        _Pragma("unroll")                                                     \
        for (int k = 1; k < 8; ++k) { s2 += sq[12+k] - sq[1+k]; u[k] = s2; }  \
        if (cg < 5) {                                                         \
            *(float4*)hx       = make_float4(o[0], o[1], o[2], o[3]);         \
            *(float4*)(hx + 4) = make_float4(o[4], o[5], o[6], o[7]);         \
            *(float4*)hy       = make_float4(u[0], u[1], u[2], u[3]);         \
            *(float4*)(hy + 4) = make_float4(u[4], u[5], u[6], u[7]);         \
        } else {                                                              \
            *(float2*)hx = make_float2(o[0], o[1]);   /* cols 40,41 */        \
            *(float2*)hy = make_float2(u[0], u[1]);                           \
        }                                                                     \
    }

// ---- P4 half: vertical 11-sums over h1 -> A,B rows Q0..Q0+20. 77 tasks:
// chunk 0..6 (3 rows), cg 0..10 (cols 4cg..4cg+3). Buf rows rb0+d, d=0..12.
// Subtract-rows d=0..2 held in named regs.
#define P4_HALF(Q0)                                                           \
    if (tid < 77) {                                                           \
        int chunk = tid / 11, cg = tid - chunk * 11;                          \
        int rb0 = chunk * 3, c4 = cg * 4;                                     \
        float mv0 = ((unsigned)(tx0-5+c4+0) < (unsigned)W) ? INV121 : 0.f;    \
        float mv1 = ((unsigned)(tx0-5+c4+1) < (unsigned)W) ? INV121 : 0.f;    \
        float mv2 = ((unsigned)(tx0-5+c4+2) < (unsigned)W) ? INV121 : 0.f;    \
        float mv3 = ((unsigned)(tx0-5+c4+3) < (unsigned)W) ? INV121 : 0.f;    \
        const float* hx = &S[O_H1X + c4];                                     \
        const float* hy = &S[O_H1Y + c4];                                     \
        float4 sX0 = ld4(hx + (rb0+0)*H1STR), sY0 = ld4(hy + (rb0+0)*H1STR);  \
        float4 sX1 = ld4(hx + (rb0+1)*H1STR), sY1 = ld4(hy + (rb0+1)*H1STR);  \
        float4 sX2 = ld4(hx + (rb0+2)*H1STR), sY2 = ld4(hy + (rb0+2)*H1STR);  \
        float sx0 = sX0.x + sX1.x + sX2.x, sy0 = sY0.x + sY1.x + sY2.x;       \
        float sx1 = sX0.y + sX1.y + sX2.y, sy1 = sY0.y + sY1.y + sY2.y;       \
        float sx2 = sX0.z + sX1.z + sX2.z, sy2 = sY0.z + sY1.z + sY2.z;       \
        float sx3 = sX0.w + sX1.w + sX2.w, sy3 = sY0.w + sY1.w + sY2.w;       \
        _Pragma("unroll")                                                     \
        for (int d = 3; d < 10; ++d) {                                        \
            float4 xn = ld4(hx + (rb0+d)*H1STR);                              \
            float4 yn = ld4(hy + (rb0+d)*H1STR);                              \
            sx0+=xn.x; sx1+=xn.y; sx2+=xn.z; sx3+=xn.w;                       \
            sy0+=yn.x; sy1+=yn.y; sy2+=yn.z; sy3+=yn.w;                       \
        }                                                                     \
        P4_ROW(Q0, 0, sX0, sY0, 1)                                            \
        P4_ROW(Q0, 1, sX1, sY1, 1)                                            \
        P4_ROW(Q0, 2, sX2, sY2, 0)                                            \
    }

#define P4_ROW(Q0, J, SUBX, SUBY, DOSUB)                                      \
            {                                                                 \
                int q = (Q0) + rb0 + (J);                                     \
                float4 xn = ld4(hx + (rb0+10+(J))*H1STR);                     \
                float4 yn = ld4(hy + (rb0+10+(J))*H1STR);                     \
                sx0+=xn.x; sx1+=xn.y; sx2+=xn.z; sx3+=xn.w;                   \
                sy0+=yn.x; sy1+=yn.y; sy2+=yn.z; sy3+=yn.w;                   \
                int gy = ty0 - 5 + q;                                         \
                float4 av, bv;                                                \
                if ((unsigned)gy < (unsigned)W) {                             \
                    float m0=sx0*mv0, c0=sy0*mv0, m1=sx1*mv1, c1=sy1*mv1;     \
                    float m2=sx2*mv2, c2=sy2*mv2, m3=sx3*mv3, c3=sy3*mv3;     \
                    float va0=fmaf(-m0,m0,c0), va1=fmaf(-m1,m1,c1);           \
                    float va2=fmaf(-m2,m2,c2), va3=fmaf(-m3,m3,c3);           \
                    float a0=va0*__builtin_amdgcn_rcpf(va0+1e-6f);            \
                    float a1=va1*__builtin_amdgcn_rcpf(va1+1e-6f);            \
                    float a2=va2*__builtin_amdgcn_rcpf(va2+1e-6f);            \
                    float a3=va3*__builtin_amdgcn_rcpf(va3+1e-6f);            \
                    av = make_float4(a0,a1,a2,a3);                            \
                    bv = make_float4(fmaf(-a0,m0,m0), fmaf(-a1,m1,m1),        \
                                     fmaf(-a2,m2,m2), fmaf(-a3,m3,m3));       \
                } else { av = make_float4(0.f,0.f,0.f,0.f); bv = av; }        \
                *(float4*)&S[O_A + q*ABSTR + c4] = av;                        \
                *(float4*)&S[O_B + q*ABSTR + c4] = bv;                        \
                if (DOSUB) {                                                  \
                    sx0-=SUBX.x; sx1-=SUBX.y; sx2-=SUBX.z; sx3-=SUBX.w;       \
                    sy0-=SUBY.x; sy1-=SUBY.y; sy2-=SUBY.z; sy3-=SUBY.w;       \
                }                                                             \
            }

__global__ __launch_bounds__(256, 4) void sgf_loss_kernel(
    const float* __restrict__ gen, const float* __restrict__ ir,
    const float* __restrict__ vi, float* __restrict__ partials)
{
    __shared__ __align__(16) float S[S_FLOATS];
    const int tid = threadIdx.x;

    // XCD-chunked bijective swizzle (NWG % 8 == 0)
    const int bid = blockIdx.x;
    const int swz = (bid & 7) * (NWG / 8) + (bid >> 3);
    const int tx0 = (swz & (NBLK_X - 1)) * TB;
    const int ty0 = ((swz / NBLK_X) & (NBLK_Y - 1)) * TB;
    const size_t pbase = (size_t)(swz / (NBLK_X * NBLK_Y)) * (W * W);

    float acc = 0.0f;
    float F0 = 0.f, F1 = 0.f, F2 = 0.f, F3 = 0.f;   // flit state (named regs)

    #pragma unroll 1
    for (int img = 0; img < 3; ++img) {
        const float* __restrict__ X =
            (img == 0 ? ir : (img == 1 ? vi : gen)) + pbase;

        __syncthreads();   // prev P7's h2 reads (region1) done before P2a writes

        P2_HALF(ty0 - 10)          // h1 rows <- img rows ty0-10 .. ty0+20
        __syncthreads();
        P4_HALF(0)                 // A,B rows 0..20
        __syncthreads();
        P2_HALF(ty0 + 11)          // h1 rows <- img rows ty0+11 .. ty0+41
        __syncthreads();
        P4_HALF(21)                // A,B rows 21..41
        __syncthreads();

        // ---- P6: horizontal 11-sums of a,b -> h2a,h2b (region1; h1 dead).
        // 168 tasks (r 0..41, cg 0..3 -> 8 output cols each).
        if (tid < 168) {
            int r = tid >> 2, cg = tid & 3;
            int j0 = cg * 8;
            const float* Ap = &S[O_A + r * ABSTR + j0];
            const float* Bp = &S[O_B + r * ABSTR + j0];
            float wa[20], wb[20];
            #pragma unroll
            for (int k = 0; k < 5; ++k) {
                float4 va = ld4(Ap + 4 * k);
                wa[4*k]=va.x; wa[4*k+1]=va.y; wa[4*k+2]=va.z; wa[4*k+3]=va.w;
                float4 vb = ld4(Bp + 4 * k);
                wb[4*k]=vb.x; wb[4*k+1]=vb.y; wb[4*k+2]=vb.z; wb[4*k+3]=vb.w;
            }
            float oa[8], ob[8];
            float s = wa[0]+wa[1]+wa[2]+wa[3]+wa[4]+wa[5]+wa[6]+wa[7]+wa[8]+wa[9]+wa[10];
            oa[0] = s;
            #pragma unroll
            for (int k = 1; k < 8; ++k) { s += wa[10+k] - wa[k-1]; oa[k] = s; }
            float s2 = wb[0]+wb[1]+wb[2]+wb[3]+wb[4]+wb[5]+wb[6]+wb[7]+wb[8]+wb[9]+wb[10];
            ob[0] = s2;
            #pragma unroll
            for (int k = 1; k < 8; ++k) { s2 += wb[10+k] - wb[k-1]; ob[k] = s2; }
            float* da = &S[O_H2A + r * H2STR + j0];
            float* db = &S[O_H2B + r * H2STR + j0];
            *(float4*)da       = make_float4(oa[0], oa[1], oa[2], oa[3]);
            *(float4*)(da + 4) = make_float4(oa[4], oa[5], oa[6], oa[7]);
            *(float4*)db       = make_float4(ob[0], ob[1], ob[2], ob[3]);
            *(float4*)(db + 4) = make_float4(ob[4], ob[5], ob[6], ob[7]);
        }
        __syncthreads();

        // ---- P7: DIRECT 11-tap vertical over h2 -> f; 256 tasks (all waves).
        // r = tid>>3 (out row 0..31), cg = tid&7 (cols 4cg..4cg+3).
        {
            int r = tid >> 3, c4 = (tid & 7) * 4;
            const float* ha = &S[O_H2A + c4];
            const float* hb = &S[O_H2B + c4];
            float sa0=0,sa1=0,sa2=0,sa3=0, sb0=0,sb1=0,sb2=0,sb3=0;
            #pragma unroll
            for (int d = 0; d < 11; ++d) {
                float4 a = ld4(ha + (r+d)*H2STR);
                float4 b = ld4(hb + (r+d)*H2STR);
                sa0+=a.x; sa1+=a.y; sa2+=a.z; sa3+=a.w;
                sb0+=b.x; sb1+=b.y; sb2+=b.z; sb3+=b.w;
            }
            float4 xv = ld4(X + (size_t)(ty0 + r) * W + (tx0 + c4));
            float t0 = fmaf(sa0, xv.x, sb0), g0 = fmaf(-t0, INV121, xv.x);
            float t1 = fmaf(sa1, xv.y, sb1), g1 = fmaf(-t1, INV121, xv.y);
            float t2 = fmaf(sa2, xv.z, sb2), g2 = fmaf(-t2, INV121, xv.z);
            float t3 = fmaf(sa3, xv.w, sb3), g3 = fmaf(-t3, INV121, xv.w);
            if (img == 0) {
                F0 = fabsf(g0); F1 = fabsf(g1); F2 = fabsf(g2); F3 = fabsf(g3);
            } else if (img == 1) {
                F0 = fmaxf(F0, fabsf(g0)); F1 = fmaxf(F1, fabsf(g1));
                F2 = fmaxf(F2, fabsf(g2)); F3 = fmaxf(F3, fabsf(g3));
            } else {
                acc += fabsf(g0 - F0) + fabsf(g1 - F1)
                     + fabsf(g2 - F2) + fabsf(g3 - F3);
            }
        }
    } // img loop

    // block reduction: wave shuffle + cross-wave via LDS
    #pragma unroll
    for (int off = 32; off > 0; off >>= 1) acc += __shfl_down(acc, off);
    __syncthreads();                // all P7 LDS reads done before S reuse
    if ((tid & 63) == 0) S[tid >> 6] = acc;
    __syncthreads();
    if (tid == 0)
        partials[swz] = S[0] + S[1] + S[2] + S[3];
}

__global__ __launch_bounds__(256) void sgf_final_reduce(
    const float* __restrict__ partials, float* __restrict__ out)
{
    __shared__ double sd[256];
    int tid = threadIdx.x;
    double s = 0.0;
    for (int i = tid; i < NPARTIALS; i += 256) s += (double)partials[i];
    sd[tid] = s;
    __syncthreads();
    for (int off = 128; off > 0; off >>= 1) {
        if (tid < off) sd[tid] += sd[tid + off];
        __syncthreads();
    }
    if (tid == 0) out[0] = (float)(sd[0] * (1.0 / TOTAL_ELEMS));
}

extern "C" void kernel_launch(void* const* d_in, const int* in_sizes, int n_in,
                              void* d_out, int out_size, void* d_ws, size_t ws_size,
                              hipStream_t stream) {
    const float* gen = (const float*)d_in[0];
    const float* ir  = (const float*)d_in[1];
    const float* vi  = (const float*)d_in[2];
    float* partials = (float*)d_ws;   // 6144 floats = 24 KB

    sgf_loss_kernel<<<dim3(NWG), dim3(256), 0, stream>>>(gen, ir, vi, partials);
    sgf_final_reduce<<<1, dim3(256), 0, stream>>>(partials, (float*)d_out);
}